// Round 1
// baseline (521.466 us; speedup 1.0000x reference)
//
#include <hip/hip_runtime.h>
#include <math.h>

#define NFFT   1024
#define HOPS   256
#define WINL   1024
#define PADL   384
#define BATCH  16
#define NFRAMES 2048
#define SPEC_K 513
#define SPEC_T 2048
#define OUT_PER_B  524288   // (NFRAMES-1)*HOP + WIN - 2*PAD
#define FULL_PER_B 525056   // (NFRAMES-1)*HOP + WIN

#define COLS 10      // frames per block
#define STRIDEF 7    // finalize stride in frames (blocks overlap by 3 frames)
#define JBLK 293     // blocks per batch (j = 0..292 covers finalize [0, 525056))
#define OASPAN 3328  // (COLS-1)*HOP + WIN floats of overlap-add buffer

struct C2 { float x, y; };

__device__ __forceinline__ C2 cadd(C2 a, C2 b){ return {a.x+b.x, a.y+b.y}; }
__device__ __forceinline__ C2 csub(C2 a, C2 b){ return {a.x-b.x, a.y-b.y}; }
__device__ __forceinline__ C2 cmul(C2 a, C2 b){ return {a.x*b.x - a.y*b.y, a.x*b.y + a.y*b.x}; }
__device__ __forceinline__ C2 muli(C2 a){ return {-a.y, a.x}; }   // multiply by +i

// y[j] = sum_i x[i] * e^{+2*pi*i * i*j / 8}   (8-point inverse DFT, no scale)
__device__ __forceinline__ void idft8(C2* v) {
    C2 e0=v[0], e1=v[2], e2=v[4], e3=v[6];
    C2 o0=v[1], o1=v[3], o2=v[5], o3=v[7];
    C2 a0=cadd(e0,e2), a1=csub(e0,e2), a2=cadd(e1,e3), a3=csub(e1,e3);
    C2 E0=cadd(a0,a2), E1=cadd(a1,muli(a3)), E2=csub(a0,a2), E3=csub(a1,muli(a3));
    C2 b0=cadd(o0,o2), b1=csub(o0,o2), b2=cadd(o1,o3), b3=csub(o1,o3);
    C2 O0=cadd(b0,b2), O1=cadd(b1,muli(b3)), O2=csub(b0,b2), O3=csub(b1,muli(b3));
    const float s = 0.7071067811865476f;
    C2 t1 = {  s*(O1.x - O1.y), s*(O1.x + O1.y) };   // w8^1 * O1
    C2 t2 = muli(O2);                                 // w8^2 * O2
    C2 t3 = { -s*(O3.x + O3.y), s*(O3.x - O3.y) };   // w8^3 * O3
    v[0]=cadd(E0,O0); v[4]=csub(E0,O0);
    v[1]=cadd(E1,t1); v[5]=csub(E1,t1);
    v[2]=cadd(E2,t2); v[6]=csub(E2,t2);
    v[3]=cadd(E3,t3); v[7]=csub(E3,t3);
}

// LDS index padding to spread banks across 64-complex strides
__device__ __forceinline__ int IDX(int x){ return x + 3*(x>>6); }

__global__ __launch_bounds__(256, 2)
void istft_kernel(const float* __restrict__ sr, const float* __restrict__ si,
                  const float* __restrict__ win, float* __restrict__ out)
{
    __shared__ C2    wbuf[COLS][536];   // per-frame packed spectrum / FFT workspace
    __shared__ float oa[OASPAN];        // overlap-add accumulator
    __shared__ float swin[WINL];
    __shared__ C2    tw3[512];          // e^{2pi i a*u/512}, [a*64+u]
    __shared__ C2    tw2[64];           // e^{2pi i b*m0/64}, [b*8+m0]

    // XCD-aware swizzle: consecutive logical j on the same XCD (L2 reuse of 3-frame overlap)
    int h  = blockIdx.x;
    int L  = (h & 7) * (BATCH*JBLK/8) + (h >> 3);
    int b  = L / JBLK;
    int j  = L - b*JBLK;
    int t0 = j * STRIDEF;
    int tid = threadIdx.x;

    // ---- phase 0: tables, window, OA zero ----
    for (int i = tid; i < WINL; i += 256) swin[i] = win[i];
    for (int i = tid; i < OASPAN; i += 256) oa[i] = 0.f;
    if (tid < 64) {
        int bb = tid >> 3, m0 = tid & 7;
        float a = (float)(bb*m0) * 0.09817477042468103f;   // 2pi/64
        float sn, cs; __sincosf(a, &sn, &cs);
        tw2[tid] = {cs, sn};
    }
    for (int i = tid; i < 512; i += 256) {
        int aa = i >> 6, uu = i & 63;
        float a = (float)(aa*uu) * 0.012271846303085129f;  // 2pi/512
        float sn, cs; __sincosf(a, &sn, &cs);
        tw3[i] = {cs, sn};
    }

    // ---- phase 1: global load + pack to W[k] = (E[k] + i*O[k]) / 512 ----
    const float* srb = sr + (size_t)b * SPEC_K * SPEC_T;
    const float* sib = si + (size_t)b * SPEC_K * SPEC_T;
    const float inv512 = 1.0f/512.0f;
    const int ncells = 257 * COLS;   // k-pairs 0..256 x COLS frames
    for (int c = tid; c < ncells; c += 256) {
        int kp = c / COLS;
        int tt = c - kp*COLS;
        int t  = t0 + tt;
        if (t < NFRAMES) {
            int krev = 512 - kp;
            float Ar = srb[kp*SPEC_T + t];
            float Ai = sib[kp*SPEC_T + t];
            float Br = srb[krev*SPEC_T + t];
            float Bi = sib[krev*SPEC_T + t];
            if (kp == 0) { Ai = 0.f; Bi = 0.f; }   // irfft ignores imag of bins 0 and 512
            float Er = 0.5f*(Ar+Br), Ei = 0.5f*(Ai-Bi);
            float Dr = 0.5f*(Ar-Br), Di = 0.5f*(Ai+Bi);
            float ang = (float)kp * 0.006135923151542565f;  // 2pi/1024
            float ss, cc; __sincosf(ang, &ss, &cc);
            float Or = cc*Dr - ss*Di, Oi = cc*Di + ss*Dr;
            wbuf[tt][IDX(kp)] = { (Er - Oi)*inv512, (Ei + Or)*inv512 };
            if (kp > 0)
                wbuf[tt][IDX(512-kp)] = { (Er + Oi)*inv512, (Or - Ei)*inv512 };
        }
    }
    __syncthreads();

    // ---- phase 2: per-wave 512-pt inverse FFT (3 x radix-8, in-place) + windowed OA ----
    int wave = tid >> 6, lane = tid & 63;
    for (int col = wave; col < COLS; col += 4) {
        int t = t0 + col;
        if (t >= NFRAMES) continue;
        C2* buf = wbuf[col];
        C2 v[8];

        // stage 1: k = lane + 64c  ->  [lane + 64*m0]
        #pragma unroll
        for (int c = 0; c < 8; ++c) v[c] = buf[IDX(lane + 64*c)];
        idft8(v);
        #pragma unroll
        for (int m0 = 0; m0 < 8; ++m0) buf[IDX(lane + 64*m0)] = v[m0];

        // stage 2: read [a + 8b + 64m0], twiddle e^{2pi i b m0/64}, -> [a + 8m1 + 64m0]
        int a2 = lane & 7, m02 = lane >> 3;
        #pragma unroll
        for (int bb = 0; bb < 8; ++bb) v[bb] = buf[IDX(a2 + 8*bb + 64*m02)];
        #pragma unroll
        for (int bb = 1; bb < 8; ++bb) v[bb] = cmul(v[bb], tw2[bb*8 + m02]);
        idft8(v);
        #pragma unroll
        for (int m1 = 0; m1 < 8; ++m1) buf[IDX(a2 + 8*m1 + 64*m02)] = v[m1];

        // stage 3: read [8*lane + a] (contig), twiddle e^{2pi i a u/512}, u = m0+8m1
        int m03 = lane >> 3, m13 = lane & 7;
        int up = m03 + 8*m13;
        #pragma unroll
        for (int aa = 0; aa < 8; ++aa) v[aa] = buf[IDX(8*lane + aa)];
        #pragma unroll
        for (int aa = 1; aa < 8; ++aa) v[aa] = cmul(v[aa], tw3[aa*64 + up]);
        idft8(v);

        // unpack z[m] -> x[2m], x[2m+1]; window; overlap-add (LDS atomics: waves overlap)
        int obase = col * HOPS;
        #pragma unroll
        for (int m2 = 0; m2 < 8; ++m2) {
            int n = 2*(up + 64*m2);
            atomicAdd(&oa[obase + n],     v[m2].x * swin[n]);
            atomicAdd(&oa[obase + n + 1], v[m2].y * swin[n+1]);
        }
    }
    __syncthreads();

    // ---- phase 3: finalize exclusive span with envelope division ----
    int p_start = (j == 0) ? 0 : (t0 + 3) * HOPS;
    int p_end   = (t0 + COLS) * HOPS;
    if (p_end > FULL_PER_B) p_end = FULL_PER_B;
    float* outb = out + (size_t)b * OUT_PER_B;
    for (int p = p_start + tid; p < p_end; p += 256) {
        int o = p - PADL;
        if (o < 0 || o >= OUT_PER_B) continue;
        int thi = p >> 8; if (thi > NFRAMES-1) thi = NFRAMES-1;
        int tlo = (p - 768) >> 8; if (tlo < 0) tlo = 0;   // ceil((p-1023)/256)
        float env = 0.f;
        for (int t = tlo; t <= thi; ++t) {
            float w = swin[p - (t << 8)];
            env += w * w;
        }
        env = fmaxf(env, 1e-11f);
        outb[o] = oa[p - t0*HOPS] / env;
    }
}

extern "C" void kernel_launch(void* const* d_in, const int* in_sizes, int n_in,
                              void* d_out, int out_size, void* d_ws, size_t ws_size,
                              hipStream_t stream) {
    const float* sr  = (const float*)d_in[0];
    const float* si  = (const float*)d_in[1];
    const float* win = (const float*)d_in[2];
    float* out = (float*)d_out;
    istft_kernel<<<dim3(BATCH*JBLK), dim3(256), 0, stream>>>(sr, si, win, out);
}

// Round 2
// 230.874 us; speedup vs baseline: 2.2587x; 2.2587x over previous
//
#include <hip/hip_runtime.h>
#include <math.h>

#define NFFT   1024
#define HOPS   256
#define WINL   1024
#define PADL   384
#define BATCH  16
#define NFRAMES 2048
#define SPEC_K 513
#define SPEC_T 2048
#define OUT_PER_B  524288   // (NFRAMES-1)*HOP + WIN - 2*PAD
#define FULL_PER_B 525056   // (NFRAMES-1)*HOP + WIN

#define COLS 8       // frames per block
#define STRIDEF 5    // finalize stride in frames (blocks overlap by 3 frames)
#define JBLK 410     // blocks per batch: (409*5+8)*256 >= 525056
#define FSTRIDE 540  // C2 elements per frame row (padded: breaks phase-1 write conflicts)

struct C2 { float x, y; };

__device__ __forceinline__ C2 cadd(C2 a, C2 b){ return {a.x+b.x, a.y+b.y}; }
__device__ __forceinline__ C2 csub(C2 a, C2 b){ return {a.x-b.x, a.y-b.y}; }
__device__ __forceinline__ C2 cmul(C2 a, C2 b){ return {a.x*b.x - a.y*b.y, a.x*b.y + a.y*b.x}; }
__device__ __forceinline__ C2 muli(C2 a){ return {-a.y, a.x}; }   // multiply by +i

// 8-point inverse DFT (no scale): y[j] = sum_i x[i] e^{+2pi i * i*j/8}
__device__ __forceinline__ void idft8(C2* v) {
    C2 e0=v[0], e1=v[2], e2=v[4], e3=v[6];
    C2 o0=v[1], o1=v[3], o2=v[5], o3=v[7];
    C2 a0=cadd(e0,e2), a1=csub(e0,e2), a2=cadd(e1,e3), a3=csub(e1,e3);
    C2 E0=cadd(a0,a2), E1=cadd(a1,muli(a3)), E2=csub(a0,a2), E3=csub(a1,muli(a3));
    C2 b0=cadd(o0,o2), b1=csub(o0,o2), b2=cadd(o1,o3), b3=csub(o1,o3);
    C2 O0=cadd(b0,b2), O1=cadd(b1,muli(b3)), O2=csub(b0,b2), O3=csub(b1,muli(b3));
    const float s = 0.7071067811865476f;
    C2 t1 = {  s*(O1.x - O1.y), s*(O1.x + O1.y) };
    C2 t2 = muli(O2);
    C2 t3 = { -s*(O3.x + O3.y), s*(O3.x - O3.y) };
    v[0]=cadd(E0,O0); v[4]=csub(E0,O0);
    v[1]=cadd(E1,t1); v[5]=csub(E1,t1);
    v[2]=cadd(E2,t2); v[6]=csub(E2,t2);
    v[3]=cadd(E3,t3); v[7]=csub(E3,t3);
}

// intra-frame LDS padding: +3 C2 per 64 C2 (breaks stride-64 conflicts in FFT stages)
__device__ __forceinline__ int IDX(int x){ return x + 3*(x>>6); }

__global__ __launch_bounds__(256, 4)
void istft_kernel(const float* __restrict__ sr, const float* __restrict__ si,
                  const float* __restrict__ win, float* __restrict__ out)
{
    __shared__ C2    fbuf[COLS][FSTRIDE];  // packed spectrum -> FFT workspace -> windowed frame
    __shared__ float swin[WINL];

    // XCD-aware swizzle: consecutive logical j land on the same XCD (L2 reuse of overlap)
    int h  = blockIdx.x;
    int L  = (h & 7) * (BATCH*JBLK/8) + (h >> 3);
    int b  = L / JBLK;
    int j  = L - b*JBLK;
    int t0 = j * STRIDEF;
    int tid = threadIdx.x;
    int lane = tid & 63, wave = tid >> 6;

    for (int i = tid; i < WINL; i += 256) swin[i] = win[i];

    // ---- per-lane register twiddles (lane-only dependent) ----
    int m02 = lane >> 3, a2 = lane & 7;
    int up  = m02 + 8*a2;            // stage-3 u index
    float c2r[8], c2i[8], c3r[8], c3i[8];
    #pragma unroll
    for (int q = 1; q < 8; ++q) {
        __sincosf((float)(q*m02) * 0.09817477042468103f,  &c2i[q], &c2r[q]);  // 2pi/64
        __sincosf((float)(q*up)  * 0.012271846303085129f, &c3i[q], &c3r[q]);  // 2pi/512
    }

    // ---- phase 1: global load + pack W[k] = (E[k] + i*O[k])/512 ----
    const float* srb = sr + (size_t)b * SPEC_K * SPEC_T;
    const float* sib = si + (size_t)b * SPEC_K * SPEC_T;
    const float inv512 = 1.0f/512.0f;
    const int ncells = 257 * COLS;
    for (int c = tid; c < ncells; c += 256) {
        int kp = c >> 3;         // 0..256
        int tt = c & 7;
        int t  = t0 + tt;
        if (t < NFRAMES) {
            int krev = 512 - kp;
            float Ar = srb[kp*SPEC_T + t];
            float Ai = sib[kp*SPEC_T + t];
            float Br = srb[krev*SPEC_T + t];
            float Bi = sib[krev*SPEC_T + t];
            if (kp == 0) { Ai = 0.f; Bi = 0.f; }   // irfft: bins 0/512 treated as real
            float Er = 0.5f*(Ar+Br), Ei = 0.5f*(Ai-Bi);
            float Dr = 0.5f*(Ar-Br), Di = 0.5f*(Ai+Bi);
            float ang = (float)kp * 0.006135923151542565f;  // 2pi/1024
            float ss, cc; __sincosf(ang, &ss, &cc);
            float Or = cc*Dr - ss*Di, Oi = cc*Di + ss*Dr;
            fbuf[tt][IDX(kp)] = { (Er - Oi)*inv512, (Ei + Or)*inv512 };
            if (kp > 0)
                fbuf[tt][IDX(512-kp)] = { (Er + Oi)*inv512, (Or - Ei)*inv512 };
        }
    }
    __syncthreads();

    // ---- phase 2: per-wave 512-pt inverse FFT (3 x radix-8, in-place, wave-lockstep)
    //      then windowed time-domain write-back into the same frame row ----
    for (int col = wave; col < COLS; col += 4) {
        int t = t0 + col;
        if (t >= NFRAMES) continue;
        C2* buf = fbuf[col];
        C2 v[8];

        // stage 1: [lane + 64c] -> [lane + 64m0]
        #pragma unroll
        for (int c = 0; c < 8; ++c) v[c] = buf[IDX(lane + 64*c)];
        idft8(v);
        #pragma unroll
        for (int m0 = 0; m0 < 8; ++m0) buf[IDX(lane + 64*m0)] = v[m0];

        // stage 2: [a + 8b + 64m0] --tw e^{2pi i b m0/64}--> [a + 8m1 + 64m0]
        #pragma unroll
        for (int bb = 0; bb < 8; ++bb) v[bb] = buf[IDX(a2 + 8*bb + 64*m02)];
        #pragma unroll
        for (int bb = 1; bb < 8; ++bb) v[bb] = cmul(v[bb], {c2r[bb], c2i[bb]});
        idft8(v);
        #pragma unroll
        for (int m1 = 0; m1 < 8; ++m1) buf[IDX(a2 + 8*m1 + 64*m02)] = v[m1];

        // stage 3: contiguous read [8*lane + a], tw e^{2pi i a u/512}, u = m0+8m1
        #pragma unroll
        for (int aa = 0; aa < 8; ++aa) v[aa] = buf[IDX(8*lane + aa)];
        #pragma unroll
        for (int aa = 1; aa < 8; ++aa) v[aa] = cmul(v[aa], {c3r[aa], c3i[aa]});
        idft8(v);

        // unpack z[m] -> x[2m], x[2m+1]; apply window; write frame as floats (contiguous)
        float* f = (float*)buf;
        #pragma unroll
        for (int m2 = 0; m2 < 8; ++m2) {
            int n = 2*(up + 64*m2);
            float2 val = { v[m2].x * swin[n], v[m2].y * swin[n+1] };
            *(float2*)&f[n] = val;
        }
    }
    __syncthreads();

    // ---- phase 3: finalize exclusive span: sum <=4 windowed frames + env division ----
    int p_start = (j == 0) ? 0 : (t0 + 3) * HOPS;
    int p_end   = (t0 + COLS) * HOPS;
    if (p_end > FULL_PER_B) p_end = FULL_PER_B;
    float* outb = out + (size_t)b * OUT_PER_B;
    for (int p = p_start + tid; p < p_end; p += 256) {
        int o = p - PADL;
        if (o < 0 || o >= OUT_PER_B) continue;
        int thi = p >> 8;          if (thi > NFRAMES-1) thi = NFRAMES-1;
        int tlo = (p - 768) >> 8;  if (tlo < 0) tlo = 0;
        float sum = 0.f, env = 0.f;
        for (int t = tlo; t <= thi; ++t) {
            int n = p - (t << 8);
            float w = swin[n];
            sum += ((float*)fbuf[t - t0])[n];
            env += w * w;
        }
        outb[o] = sum / fmaxf(env, 1e-11f);
    }
}

extern "C" void kernel_launch(void* const* d_in, const int* in_sizes, int n_in,
                              void* d_out, int out_size, void* d_ws, size_t ws_size,
                              hipStream_t stream) {
    const float* sr  = (const float*)d_in[0];
    const float* si  = (const float*)d_in[1];
    const float* win = (const float*)d_in[2];
    float* out = (float*)d_out;
    istft_kernel<<<dim3(BATCH*JBLK), dim3(256), 0, stream>>>(sr, si, win, out);
}